// Round 7
// baseline (126961.597 us; speedup 1.0000x reference)
//
#include <hip/hip_runtime.h>
#include <hip/hip_fp16.h>
#include <math.h>

#define H      1024
#define LBLP1  33        // LABEL_SIZE + 1
#define NE     4096
#define NS     4096
#define NSTEP  (NE - 1)  // 4095 scan steps
#define TGT    1
#define NWG    256       // launched WGs (election picks 32 on one XCD)
#define SLOTS  32        // scan workgroups (one XCD)
#define UPS    32        // hidden units per slot
#define SROWS  224       // 7 gates * 32 units per slot
#define THREADS 1024
#define RPW    14        // rows per wave (224 / 16 waves)
#define NLDS   4         // rows per wave staged in LDS
#define NREG   10        // rows per wave staged in registers
#define SENT   0xFFFFFFFFu

__device__ __forceinline__ float wave_sum(float v) {
#pragma unroll
    for (int o = 32; o > 0; o >>= 1) v += __shfl_xor(v, o, 64);
    return v;
}
__device__ __forceinline__ float softplusf(float x) {
    return x > 0.f ? x + log1pf(expf(-x)) : log1pf(expf(x));
}
__device__ __forceinline__ float sigmoidf(float x) {
    return 1.f / (1.f + expf(-x));
}

// f16x2 dot into fp32 accumulator via unpack + 2 fma (portable HIP API)
__device__ __forceinline__ float dot2(unsigned u, unsigned h, float c) {
    float2 fa = __half22float2(__builtin_bit_cast(__half2, u));
    float2 fb = __half22float2(__builtin_bit_cast(__half2, h));
    c = fmaf(fa.x, fb.x, c);
    c = fmaf(fa.y, fb.y, c);
    return c;
}

__device__ __forceinline__ unsigned pkhalf2(float a, float b) {
    return __builtin_bit_cast(unsigned, __floats2half2_rn(a, b));
}

// EmbT[l*H + k] = Emb[k*LBLP1 + l]
__global__ void embT_kernel(const float* __restrict__ Emb, float* __restrict__ EmbT) {
    int l = blockIdx.x;
    for (int k = threadIdx.x; k < H; k += blockDim.x)
        EmbT[(size_t)l * H + k] = Emb[(size_t)k * LBLP1 + l];
}

// WEmb[row*33 + l] = dot(W[row,:], EmbT[l,:]) + d[row]
__global__ void wemb_kernel(const float* __restrict__ W, const float* __restrict__ EmbT,
                            const float* __restrict__ dbias, float* __restrict__ WEmb) {
    int row  = blockIdx.x;
    int wave = threadIdx.x >> 6;
    int lane = threadIdx.x & 63;
    __shared__ float wrow[H];
    for (int i = threadIdx.x; i < H; i += blockDim.x) wrow[i] = W[(size_t)row * H + i];
    __syncthreads();
    float db = dbias[row];
    for (int l = wave; l < LBLP1; l += 4) {
        const float* ec = EmbT + (size_t)l * H;
        float a = 0.f;
#pragma unroll
        for (int m = 0; m < 16; ++m) {
            int k = lane + (m << 6);
            a = fmaf(wrow[k], ec[k], a);
        }
        a = wave_sum(a);
        if (lane == 0) WEmb[(size_t)row * LBLP1 + l] = a + db;
    }
}

// pack U rows fp32 -> f16x2 dwords: Upk[row][p] holds elems (2p, 2p+1)
__global__ void upk_kernel(const float* __restrict__ U, unsigned* __restrict__ Upk) {
    int row = blockIdx.x;  // 0..7*H-1
    const float4* src = (const float4*)(U + (size_t)row * H);
    uint2* dst = (uint2*)(Upk + (size_t)row * (H / 2));
    for (int j = threadIdx.x; j < H / 4; j += blockDim.x) {
        float4 f = src[j];
        dst[j] = make_uint2(pkhalf2(f.x, f.y), pkhalf2(f.z, f.w));
    }
}

// Single-XCD persistent scan. 256 WGs launched; 32 on one XCD elected.
// Slot s owns units [32s, 32s+32) for all 7 gates (224 U rows, f16).
// h exchange via XCD-local L2 (sc0 loads; sc0+sc1 write-through stores).
__global__ __launch_bounds__(THREADS)
void scan_kernel(const unsigned* __restrict__ Upk, const float* __restrict__ WEmb,
                 const int* __restrict__ label_seq, const float* __restrict__ time_seq,
                 int* __restrict__ ctl, unsigned* __restrict__ hpub,
                 float* __restrict__ all_h, float* __restrict__ all_o,
                 float* __restrict__ all_cb, float* __restrict__ all_cc,
                 float* __restrict__ all_dl) {
    const int tid  = threadIdx.x;
    const int wave = tid >> 6;
    const int lane = tid & 63;

    // ---------------- election ----------------
    __shared__ int s_slot;
    if (tid == 0) {
        unsigned xcc;
        asm volatile("s_getreg_b32 %0, hwreg(HW_REG_XCC_ID)" : "=s"(xcc));
        int myslot = atomicAdd(&ctl[xcc & 7], 1);
        if (myslot == SLOTS - 1) atomicCAS(&ctl[8], -1, (int)(xcc & 7));
        int win;
        while ((win = __hip_atomic_load(&ctl[8], __ATOMIC_RELAXED,
                                        __HIP_MEMORY_SCOPE_AGENT)) < 0)
            __builtin_amdgcn_s_sleep(8);
        s_slot = ((int)(xcc & 7) == win && myslot < SLOTS) ? myslot : -1;
    }
    __syncthreads();
    const int slot = s_slot;
    if (slot < 0) return;

    // ---------------- LDS layout (dwords) ----------------
    extern __shared__ unsigned smem_u[];
    unsigned* uldz   = smem_u;                    // 64 rows * 512 = 32768
    unsigned* h_pk   = uldz + 64 * 512;           // 512
    unsigned* wespk  = h_pk + 512;                // 224*17 = 3808
    float*    act_sh = (float*)(wespk + SROWS * 17);   // 224
    float*    part8  = act_sh + SROWS;            // 8 * 225 = 1800

    // ---------------- one-time staging ----------------
    unsigned ureg[NREG][8];
    {
        // this wave's 4 LDS rows
#pragma unroll
        for (int i = 0; i < NLDS; ++i) {
            int r = wave * RPW + i;
            int e = r >> 5, j = r & 31;
            size_t grow = ((size_t)e * H + slot * UPS + j) * (H / 2);
#pragma unroll
            for (int m = 0; m < 8; ++m)
                uldz[(wave * NLDS + i) * 512 + lane + (m << 6)] =
                    Upk[grow + lane + (m << 6)];
        }
        // this wave's 10 register rows
#pragma unroll
        for (int i = 0; i < NREG; ++i) {
            int r = wave * RPW + NLDS + i;
            int e = r >> 5, j = r & 31;
            size_t grow = ((size_t)e * H + slot * UPS + j) * (H / 2);
#pragma unroll
            for (int m = 0; m < 8; ++m)
                ureg[i][m] = Upk[grow + lane + (m << 6)];
        }
        // gate-bias table, packed f16x2 by label pairs
        for (int idx = tid; idx < SROWS * 17; idx += THREADS) {
            int r = idx / 17, dp = idx - r * 17;
            int e = r >> 5, j = r & 31;
            size_t base = ((size_t)e * H + slot * UPS + j) * LBLP1;
            float f0 = WEmb[base + 2 * dp];
            float f1 = (2 * dp + 1 < LBLP1) ? WEmb[base + 2 * dp + 1] : 0.f;
            wespk[idx] = pkhalf2(f0, f1);
        }
    }
    __syncthreads();

    float cst0 = 0.f, cst1 = 0.f, cbs0 = 0.f, cbs1 = 0.f;  // D-thread state (2 units)

    for (int t = 0; t < NSTEP; ++t) {
        // ---- phase A: wave 0 acquires h_t from XCD-local L2 ----
        if (wave == 0) {
            unsigned v0, v1, v2, v3, v4, v5, v6, v7;
            if (t > 0) {
                const unsigned* src = hpub + (size_t)(t - 1) * 512 + lane;
                int spin = 0;
                for (;;) {
                    if ((spin & 15) == 15) {
                        // liveness fallback: coherent-point loads
                        v0 = __hip_atomic_load(src + 0,   __ATOMIC_RELAXED, __HIP_MEMORY_SCOPE_AGENT);
                        v1 = __hip_atomic_load(src + 64,  __ATOMIC_RELAXED, __HIP_MEMORY_SCOPE_AGENT);
                        v2 = __hip_atomic_load(src + 128, __ATOMIC_RELAXED, __HIP_MEMORY_SCOPE_AGENT);
                        v3 = __hip_atomic_load(src + 192, __ATOMIC_RELAXED, __HIP_MEMORY_SCOPE_AGENT);
                        v4 = __hip_atomic_load(src + 256, __ATOMIC_RELAXED, __HIP_MEMORY_SCOPE_AGENT);
                        v5 = __hip_atomic_load(src + 320, __ATOMIC_RELAXED, __HIP_MEMORY_SCOPE_AGENT);
                        v6 = __hip_atomic_load(src + 384, __ATOMIC_RELAXED, __HIP_MEMORY_SCOPE_AGENT);
                        v7 = __hip_atomic_load(src + 448, __ATOMIC_RELAXED, __HIP_MEMORY_SCOPE_AGENT);
                    } else {
                        asm volatile(
                            "global_load_dword %0, %8, off sc0\n\t"
                            "global_load_dword %1, %8, off offset:256 sc0\n\t"
                            "global_load_dword %2, %8, off offset:512 sc0\n\t"
                            "global_load_dword %3, %8, off offset:768 sc0\n\t"
                            "global_load_dword %4, %8, off offset:1024 sc0\n\t"
                            "global_load_dword %5, %8, off offset:1280 sc0\n\t"
                            "global_load_dword %6, %8, off offset:1536 sc0\n\t"
                            "global_load_dword %7, %8, off offset:1792 sc0\n\t"
                            "s_waitcnt vmcnt(0)"
                            : "=&v"(v0), "=&v"(v1), "=&v"(v2), "=&v"(v3),
                              "=&v"(v4), "=&v"(v5), "=&v"(v6), "=&v"(v7)
                            : "v"(src)
                            : "memory");
                    }
                    bool ok = (v0 != SENT) & (v1 != SENT) & (v2 != SENT) & (v3 != SENT)
                            & (v4 != SENT) & (v5 != SENT) & (v6 != SENT) & (v7 != SENT);
                    if (ok) break;
                    ++spin;
                }
            } else {
                v0 = v1 = v2 = v3 = v4 = v5 = v6 = v7 = 0u;
            }
            h_pk[lane +   0] = v0;  h_pk[lane +  64] = v1;
            h_pk[lane + 128] = v2;  h_pk[lane + 192] = v3;
            h_pk[lane + 256] = v4;  h_pk[lane + 320] = v5;
            h_pk[lane + 384] = v6;  h_pk[lane + 448] = v7;
        }
        __syncthreads();   // bar_A

        // ---- phase B: 14 f16-dot rows per wave ----
        {
            unsigned hreg[8];
#pragma unroll
            for (int m = 0; m < 8; ++m) hreg[m] = h_pk[lane + (m << 6)];

            float p[RPW];
#pragma unroll
            for (int i = 0; i < NLDS; ++i) {
                float a = 0.f;
#pragma unroll
                for (int m = 0; m < 8; ++m)
                    a = dot2(uldz[(wave * NLDS + i) * 512 + lane + (m << 6)],
                             hreg[m], a);
                p[i] = a;
            }
#pragma unroll
            for (int i = 0; i < NREG; ++i) {
                float a = 0.f;
#pragma unroll
                for (int m = 0; m < 8; ++m)
                    a = dot2(ureg[i][m], hreg[m], a);
                p[NLDS + i] = a;
            }
            // 3-level butterfly -> 8 partials per row; write to part8
#pragma unroll
            for (int i = 0; i < RPW; ++i) {
                float a = p[i];
                a += __shfl_xor(a, 1, 64);
                a += __shfl_xor(a, 2, 64);
                a += __shfl_xor(a, 4, 64);
                if ((lane & 7) == 0)
                    part8[(lane >> 3) * 225 + wave * RPW + i] = a;
            }
        }
        __syncthreads();   // bar_B

        // ---- phase C: final reduce + bias + activation (224 threads) ----
        if (tid < SROWS) {
            float s = 0.f;
#pragma unroll
            for (int k = 0; k < 8; ++k) s += part8[k * 225 + tid];
            int lab = label_seq[t];
            __half2 bp = __builtin_bit_cast(__half2, wespk[tid * 17 + (lab >> 1)]);
            float bias = (lab & 1) ? __high2float(bp) : __low2float(bp);
            float g = s + bias;
            int e = tid >> 5;
            float act;
            if (e == 2)      act = tanhf(g);
            else if (e == 6) act = softplusf(g);
            else             act = sigmoidf(g);
            act_sh[tid] = act;
        }
        __syncthreads();   // bar_C

        // ---- phase D: state update + publish (16 threads, 2 units each) ----
        if (tid < 16) {
            int q0 = 2 * tid, q1 = 2 * tid + 1;
            float dt = time_seq[t + 1] - time_seq[t];
            float ig0 = act_sh[q0],        ig1 = act_sh[q1];
            float fg0 = act_sh[32  + q0],  fg1 = act_sh[32  + q1];
            float z0  = act_sh[64  + q0],  z1  = act_sh[64  + q1];
            float oo0 = act_sh[96  + q0],  oo1 = act_sh[96  + q1];
            float ib0 = act_sh[128 + q0],  ib1 = act_sh[128 + q1];
            float fb0 = act_sh[160 + q0],  fb1 = act_sh[160 + q1];
            float dl0 = act_sh[192 + q0],  dl1 = act_sh[192 + q1];
            float c0  = fmaf(fg0, cst0, ig0 * z0);
            float c1  = fmaf(fg1, cst1, ig1 * z1);
            float cb0 = fmaf(fb0, cbs0, ib0 * z0);
            float cb1 = fmaf(fb1, cbs1, ib1 * z1);
            float ct0 = cb0 + (c0 - cb0) * expf(-dl0 * dt);
            float ct1 = cb1 + (c1 - cb1) * expf(-dl1 * dt);
            float h0  = oo0 * tanhf(ct0);
            float h1  = oo1 * tanhf(ct1);
            cst0 = ct0; cst1 = ct1; cbs0 = cb0; cbs1 = cb1;
            // publish first (critical path): f16x2, write-through to L2+IF
            unsigned pk = pkhalf2(h0, h1);
            unsigned* dst = hpub + (size_t)t * 512 + slot * 16 + tid;
            asm volatile("global_store_dword %0, %1, off sc0 sc1"
                         :: "v"(dst), "v"(pk) : "memory");
            // bookkeeping (fp32, consumed by term1/term2 after kernel end)
            size_t p = (size_t)t * H + slot * UPS + q0;
            *(float2*)&all_h [p] = make_float2(h0, h1);
            *(float2*)&all_o [p] = make_float2(oo0, oo1);
            *(float2*)&all_cb[p] = make_float2(cb0, cb1);
            *(float2*)&all_cc[p] = make_float2(c0, c1);
            *(float2*)&all_dl[p] = make_float2(dl0, dl1);
        }
        // no bar after D: wave0 proceeds to A(t+1); hazards covered by bars A-C.
    }
}

__global__ void term1_kernel(const float* __restrict__ all_h, const int* __restrict__ label_seq,
                             const float* __restrict__ w, const float* __restrict__ log_s,
                             const int* __restrict__ ignore_first, float* __restrict__ acc) {
    int beg = (*ignore_first) ? 1 : 0;
    int j = blockIdx.x;
    if (j >= (NSTEP - 1 - beg)) return;
    if (label_seq[1 + beg + j] != TGT) return;
    const float* hrow = all_h + (size_t)(beg + j) * H;
    const float* w0 = w + (TGT - 1) * H;
    float part = 0.f;
    for (int i = threadIdx.x; i < H; i += blockDim.x) part += hrow[i] * w0[i];
    __shared__ float red[4];
    part = wave_sum(part);
    if ((threadIdx.x & 63) == 0) red[threadIdx.x >> 6] = part;
    __syncthreads();
    if (threadIdx.x == 0) {
        float tot = red[0] + red[1] + red[2] + red[3];
        float s0 = expf(log_s[TGT - 1]);
        float lam = s0 * softplusf(tot / s0) + 1e-9f;
        atomicAdd(acc, logf(lam));
    }
}

__global__ void term2_kernel(const float* __restrict__ all_o, const float* __restrict__ all_cb,
                             const float* __restrict__ all_cc, const float* __restrict__ all_dl,
                             const int* __restrict__ sim_idx, const float* __restrict__ sim_time,
                             const float* __restrict__ time_seq, const float* __restrict__ w,
                             const float* __restrict__ log_s, float* __restrict__ acc) {
    int i = blockIdx.x;
    int idx = sim_idx[i];
    float dtp = sim_time[i] - time_seq[idx];
    size_t base = (size_t)idx * H;
    const float* w0 = w + (TGT - 1) * H;
    float part = 0.f;
    for (int hh = threadIdx.x; hh < H; hh += blockDim.x) {
        float cb = all_cb[base + hh];
        float cc = all_cc[base + hh];
        float dl = all_dl[base + hh];
        float oo = all_o [base + hh];
        float cs = cb + (cc - cb) * expf(-dl * dtp);
        part += oo * tanhf(cs) * w0[hh];
    }
    __shared__ float red[4];
    part = wave_sum(part);
    if ((threadIdx.x & 63) == 0) red[threadIdx.x >> 6] = part;
    __syncthreads();
    if (threadIdx.x == 0) {
        float tot = red[0] + red[1] + red[2] + red[3];
        float s0 = expf(log_s[TGT - 1]);
        float lam = s0 * softplusf(tot / s0) + 1e-9f;
        atomicAdd(acc + 1, lam);
    }
}

__global__ void finish_kernel(const float* __restrict__ acc, const float* __restrict__ time_seq,
                              float* __restrict__ out) {
    float T = time_seq[NE - 1] - time_seq[0];
    out[0] = -(acc[0] - acc[1] * (T / (float)NS));
}

extern "C" void kernel_launch(void* const* d_in, const int* in_sizes, int n_in,
                              void* d_out, int out_size, void* d_ws, size_t ws_size,
                              hipStream_t stream) {
    const int*   label_seq    = (const int*)  d_in[0];
    const float* time_seq     = (const float*)d_in[1];
    const float* sim_time     = (const float*)d_in[2];
    const int*   sim_idx      = (const int*)  d_in[3];
    const int*   ignore_first = (const int*)  d_in[4];
    const float* Emb   = (const float*)d_in[5];
    const float* W     = (const float*)d_in[6];
    const float* U     = (const float*)d_in[7];
    const float* dbias = (const float*)d_in[8];
    const float* w     = (const float*)d_in[9];
    const float* log_s = (const float*)d_in[10];
    float* out = (float*)d_out;

    float* ws = (float*)d_ws;
    size_t off = 0;
    int*      ctl  = (int*)(ws + off);      off += 16;   // [0..7] roster, [8] winner
    float*    acc  = ws + off;              off += 32;   // [0]=term1, [1]=term2-sum
    float*    EmbT = ws + off;              off += (size_t)LBLP1 * H;
    float*    WEmb = ws + off;              off += 7 * H * LBLP1;
    off = (off + 3) & ~(size_t)3;
    unsigned* Upk  = (unsigned*)(ws + off); off += (size_t)7 * H * (H / 2);
    unsigned* hpub = (unsigned*)(ws + off); off += (size_t)NSTEP * 512;
    float* all_h  = ws + off;  off += (size_t)NSTEP * H;
    float* all_o  = ws + off;  off += (size_t)NSTEP * H;
    float* all_cb = ws + off;  off += (size_t)NSTEP * H;
    float* all_cc = ws + off;  off += (size_t)NSTEP * H;
    float* all_dl = ws + off;  off += (size_t)NSTEP * H;

    hipMemsetAsync(ctl, 0, 8 * sizeof(int), stream);          // roster = 0
    hipMemsetAsync(ctl + 8, 0xFF, sizeof(int), stream);       // winner = -1
    hipMemsetAsync(acc, 0, 2 * sizeof(float), stream);
    hipMemsetAsync(hpub, 0xFF, (size_t)NSTEP * 512 * 4, stream);  // sentinel

    hipLaunchKernelGGL(embT_kernel, dim3(LBLP1), dim3(256), 0, stream, Emb, EmbT);
    hipLaunchKernelGGL(wemb_kernel, dim3(7 * H), dim3(256), 0, stream,
                       W, EmbT, dbias, WEmb);
    hipLaunchKernelGGL(upk_kernel, dim3(7 * H), dim3(256), 0, stream, U, Upk);

    // LDS: 64 U rows (32768) + h_pk (512) + wespk (3808) + act (224) + part8 (1800)
    unsigned int smem_bytes = (unsigned int)((64 * 512 + 512 + SROWS * 17 + SROWS
                                              + 8 * 225) * 4);
    hipFuncSetAttribute((const void*)scan_kernel, hipFuncAttributeMaxDynamicSharedMemorySize,
                        (int)smem_bytes);
    void* args[] = { (void*)&Upk, (void*)&WEmb, (void*)&label_seq, (void*)&time_seq,
                     (void*)&ctl, (void*)&hpub, (void*)&all_h, (void*)&all_o,
                     (void*)&all_cb, (void*)&all_cc, (void*)&all_dl };
    hipLaunchCooperativeKernel((void*)scan_kernel, dim3(NWG), dim3(THREADS),
                               args, smem_bytes, stream);

    hipLaunchKernelGGL(term1_kernel, dim3(NSTEP - 1), dim3(256), 0, stream,
                       all_h, label_seq, w, log_s, ignore_first, acc);
    hipLaunchKernelGGL(term2_kernel, dim3(NS), dim3(256), 0, stream,
                       all_o, all_cb, all_cc, all_dl, sim_idx, sim_time, time_seq, w, log_s, acc);
    hipLaunchKernelGGL(finish_kernel, dim3(1), dim3(1), 0, stream, acc, time_seq, out);
}

// Round 8
// 72758.789 us; speedup vs baseline: 1.7450x; 1.7450x over previous
//
#include <hip/hip_runtime.h>
#include <hip/hip_fp16.h>
#include <math.h>

#define H      1024
#define LBLP1  33        // LABEL_SIZE + 1
#define NE     4096
#define NS     4096
#define NSTEP  (NE - 1)  // 4095 scan steps
#define TGT    1
#define NWG    256       // launched WGs (election picks 32 on one XCD)
#define SLOTS  32        // scan workgroups (one XCD)
#define UPS    32        // hidden units per slot
#define SROWS  224       // 7 gates * 32 units per slot
#define THREADS 512
#define NWAVES 8
#define RPW    28        // rows per wave (224 / 8 waves)
#define NLDS   8         // rows per wave staged in LDS  (64 rows total = 128 KB)
#define NREG   20        // rows per wave staged in registers (160 VGPR/thread)
#define SENT   0xFFFFFFFFu

__device__ __forceinline__ float wave_sum(float v) {
#pragma unroll
    for (int o = 32; o > 0; o >>= 1) v += __shfl_xor(v, o, 64);
    return v;
}
__device__ __forceinline__ float softplusf(float x) {
    return x > 0.f ? x + log1pf(expf(-x)) : log1pf(expf(x));
}
__device__ __forceinline__ float sigmoidf(float x) {
    return 1.f / (1.f + expf(-x));
}

#if __has_builtin(__builtin_amdgcn_cvt_pkrtz) && __has_builtin(__builtin_amdgcn_fdot2)
using half2_t = decltype(__builtin_amdgcn_cvt_pkrtz(0.f, 0.f));
__device__ __forceinline__ float dot2(unsigned u, unsigned h, float c) {
    return __builtin_amdgcn_fdot2(__builtin_bit_cast(half2_t, u),
                                  __builtin_bit_cast(half2_t, h), c, false);
}
#else
__device__ __forceinline__ float dot2(unsigned u, unsigned h, float c) {
    float2 fa = __half22float2(__builtin_bit_cast(__half2, u));
    float2 fb = __half22float2(__builtin_bit_cast(__half2, h));
    c = fmaf(fa.x, fb.x, c);
    c = fmaf(fa.y, fb.y, c);
    return c;
}
#endif

__device__ __forceinline__ unsigned pkhalf2(float a, float b) {
    return __builtin_bit_cast(unsigned, __floats2half2_rn(a, b));
}

// EmbT[l*H + k] = Emb[k*LBLP1 + l]
__global__ void embT_kernel(const float* __restrict__ Emb, float* __restrict__ EmbT) {
    int l = blockIdx.x;
    for (int k = threadIdx.x; k < H; k += blockDim.x)
        EmbT[(size_t)l * H + k] = Emb[(size_t)k * LBLP1 + l];
}

// WEmb[row*33 + l] = dot(W[row,:], EmbT[l,:]) + d[row]
__global__ void wemb_kernel(const float* __restrict__ W, const float* __restrict__ EmbT,
                            const float* __restrict__ dbias, float* __restrict__ WEmb) {
    int row  = blockIdx.x;
    int wave = threadIdx.x >> 6;
    int lane = threadIdx.x & 63;
    __shared__ float wrow[H];
    for (int i = threadIdx.x; i < H; i += blockDim.x) wrow[i] = W[(size_t)row * H + i];
    __syncthreads();
    float db = dbias[row];
    for (int l = wave; l < LBLP1; l += 4) {
        const float* ec = EmbT + (size_t)l * H;
        float a = 0.f;
#pragma unroll
        for (int m = 0; m < 16; ++m) {
            int k = lane + (m << 6);
            a = fmaf(wrow[k], ec[k], a);
        }
        a = wave_sum(a);
        if (lane == 0) WEmb[(size_t)row * LBLP1 + l] = a + db;
    }
}

// pack U rows fp32 -> f16x2 dwords: Upk[row][p] holds elems (2p, 2p+1)
__global__ void upk_kernel(const float* __restrict__ U, unsigned* __restrict__ Upk) {
    int row = blockIdx.x;  // 0..7*H-1
    const float4* src = (const float4*)(U + (size_t)row * H);
    uint2* dst = (uint2*)(Upk + (size_t)row * (H / 2));
    for (int j = threadIdx.x; j < H / 4; j += blockDim.x) {
        float4 f = src[j];
        dst[j] = make_uint2(pkhalf2(f.x, f.y), pkhalf2(f.z, f.w));
    }
}

// Single-XCD persistent scan. 256 WGs launched; 32 on one XCD elected.
// Slot s owns units [32s, 32s+32) for all 7 gates (224 U rows, f16).
// h exchange entirely through the XCD-local L2: stores sc0 (write to L2,
// bypass L1), polls sc0 (read L2, bypass L1). No sc1 on the fast path.
__global__ __launch_bounds__(THREADS, 2)
void scan_kernel(const unsigned* __restrict__ Upk, const float* __restrict__ WEmb,
                 const int* __restrict__ label_seq, const float* __restrict__ time_seq,
                 int* __restrict__ ctl, unsigned* __restrict__ hpub,
                 float* __restrict__ all_h, float* __restrict__ all_o,
                 float* __restrict__ all_cb, float* __restrict__ all_cc,
                 float* __restrict__ all_dl) {
    const int tid  = threadIdx.x;
    const int wave = tid >> 6;
    const int lane = tid & 63;

    // ---------------- election ----------------
    __shared__ int s_slot;
    if (tid == 0) {
        unsigned xcc;
        asm volatile("s_getreg_b32 %0, hwreg(HW_REG_XCC_ID)" : "=s"(xcc));
        int myslot = atomicAdd(&ctl[xcc & 7], 1);
        if (myslot == SLOTS - 1) atomicCAS(&ctl[8], -1, (int)(xcc & 7));
        int win;
        while ((win = __hip_atomic_load(&ctl[8], __ATOMIC_RELAXED,
                                        __HIP_MEMORY_SCOPE_AGENT)) < 0)
            __builtin_amdgcn_s_sleep(8);
        s_slot = ((int)(xcc & 7) == win && myslot < SLOTS) ? myslot : -1;
    }
    __syncthreads();
    const int slot = s_slot;
    if (slot < 0) return;

    // ---------------- LDS layout (dwords) ----------------
    extern __shared__ unsigned smem_u[];
    unsigned* uldz   = smem_u;                    // 64 rows * 512 = 32768
    unsigned* h_pk   = uldz + 64 * 512;           // 512
    unsigned* wespk  = h_pk + 512;                // 224*17 = 3808
    float*    act_sh = (float*)(wespk + SROWS * 17);   // 224
    float*    part8  = act_sh + SROWS;            // 8 * 225 = 1800

    // ---------------- one-time staging ----------------
    unsigned ureg[NREG][8];
    {
        // this wave's 8 LDS rows
#pragma unroll
        for (int i = 0; i < NLDS; ++i) {
            int r = wave * RPW + i;
            int e = r >> 5, j = r & 31;
            size_t grow = ((size_t)e * H + slot * UPS + j) * (H / 2);
#pragma unroll
            for (int m = 0; m < 8; ++m)
                uldz[(wave * NLDS + i) * 512 + lane + (m << 6)] =
                    Upk[grow + lane + (m << 6)];
        }
        // this wave's 20 register rows
#pragma unroll
        for (int i = 0; i < NREG; ++i) {
            int r = wave * RPW + NLDS + i;
            int e = r >> 5, j = r & 31;
            size_t grow = ((size_t)e * H + slot * UPS + j) * (H / 2);
#pragma unroll
            for (int m = 0; m < 8; ++m)
                ureg[i][m] = Upk[grow + lane + (m << 6)];
        }
        // gate-bias table, packed f16x2 by label pairs
        for (int idx = tid; idx < SROWS * 17; idx += THREADS) {
            int r = idx / 17, dp = idx - r * 17;
            int e = r >> 5, j = r & 31;
            size_t base = ((size_t)e * H + slot * UPS + j) * LBLP1;
            float f0 = WEmb[base + 2 * dp];
            float f1 = (2 * dp + 1 < LBLP1) ? WEmb[base + 2 * dp + 1] : 0.f;
            wespk[idx] = pkhalf2(f0, f1);
        }
    }
    __syncthreads();

    float cst0 = 0.f, cst1 = 0.f, cbs0 = 0.f, cbs1 = 0.f;  // D-thread state (2 units)

    for (int t = 0; t < NSTEP; ++t) {
        // ---- phase A: wave 0 acquires h_t from the shared XCD L2 ----
        if (wave == 0) {
            unsigned v0, v1, v2, v3, v4, v5, v6, v7;
            if (t > 0) {
                const unsigned* src = hpub + (size_t)(t - 1) * 512 + lane;
                int spin = 0;
                for (;;) {
                    if ((spin & 63) == 63) {
                        // liveness fallback: coherent-point loads
                        v0 = __hip_atomic_load(src + 0,   __ATOMIC_RELAXED, __HIP_MEMORY_SCOPE_AGENT);
                        v1 = __hip_atomic_load(src + 64,  __ATOMIC_RELAXED, __HIP_MEMORY_SCOPE_AGENT);
                        v2 = __hip_atomic_load(src + 128, __ATOMIC_RELAXED, __HIP_MEMORY_SCOPE_AGENT);
                        v3 = __hip_atomic_load(src + 192, __ATOMIC_RELAXED, __HIP_MEMORY_SCOPE_AGENT);
                        v4 = __hip_atomic_load(src + 256, __ATOMIC_RELAXED, __HIP_MEMORY_SCOPE_AGENT);
                        v5 = __hip_atomic_load(src + 320, __ATOMIC_RELAXED, __HIP_MEMORY_SCOPE_AGENT);
                        v6 = __hip_atomic_load(src + 384, __ATOMIC_RELAXED, __HIP_MEMORY_SCOPE_AGENT);
                        v7 = __hip_atomic_load(src + 448, __ATOMIC_RELAXED, __HIP_MEMORY_SCOPE_AGENT);
                    } else {
                        asm volatile(
                            "global_load_dword %0, %8, off sc0\n\t"
                            "global_load_dword %1, %8, off offset:256 sc0\n\t"
                            "global_load_dword %2, %8, off offset:512 sc0\n\t"
                            "global_load_dword %3, %8, off offset:768 sc0\n\t"
                            "global_load_dword %4, %8, off offset:1024 sc0\n\t"
                            "global_load_dword %5, %8, off offset:1280 sc0\n\t"
                            "global_load_dword %6, %8, off offset:1536 sc0\n\t"
                            "global_load_dword %7, %8, off offset:1792 sc0\n\t"
                            "s_waitcnt vmcnt(0)"
                            : "=&v"(v0), "=&v"(v1), "=&v"(v2), "=&v"(v3),
                              "=&v"(v4), "=&v"(v5), "=&v"(v6), "=&v"(v7)
                            : "v"(src)
                            : "memory");
                    }
                    bool ok = (v0 != SENT) & (v1 != SENT) & (v2 != SENT) & (v3 != SENT)
                            & (v4 != SENT) & (v5 != SENT) & (v6 != SENT) & (v7 != SENT);
                    if (ok) break;
                    ++spin;
                }
            } else {
                v0 = v1 = v2 = v3 = v4 = v5 = v6 = v7 = 0u;
            }
            h_pk[lane +   0] = v0;  h_pk[lane +  64] = v1;
            h_pk[lane + 128] = v2;  h_pk[lane + 192] = v3;
            h_pk[lane + 256] = v4;  h_pk[lane + 320] = v5;
            h_pk[lane + 384] = v6;  h_pk[lane + 448] = v7;
        }
        __syncthreads();   // bar_A

        // ---- phase B: 28 f16-dot rows per wave (8 LDS + 20 reg) ----
        {
            unsigned hreg[8];
#pragma unroll
            for (int m = 0; m < 8; ++m) hreg[m] = h_pk[lane + (m << 6)];

            float p[RPW];
#pragma unroll
            for (int i = 0; i < NLDS; ++i) {
                float a = 0.f;
#pragma unroll
                for (int m = 0; m < 8; ++m)
                    a = dot2(uldz[(wave * NLDS + i) * 512 + lane + (m << 6)],
                             hreg[m], a);
                p[i] = a;
            }
#pragma unroll
            for (int i = 0; i < NREG; ++i) {
                float a = 0.f;
#pragma unroll
                for (int m = 0; m < 8; ++m)
                    a = dot2(ureg[i][m], hreg[m], a);
                p[NLDS + i] = a;
            }
            // 3-level butterfly -> 8 partials per row; write to part8
#pragma unroll
            for (int i = 0; i < RPW; ++i) {
                float a = p[i];
                a += __shfl_xor(a, 1, 64);
                a += __shfl_xor(a, 2, 64);
                a += __shfl_xor(a, 4, 64);
                if ((lane & 7) == 0)
                    part8[(lane >> 3) * 225 + wave * RPW + i] = a;
            }
        }
        __syncthreads();   // bar_B

        // ---- phase C: final reduce + bias + activation (224 threads) ----
        if (tid < SROWS) {
            float s = 0.f;
#pragma unroll
            for (int k = 0; k < 8; ++k) s += part8[k * 225 + tid];
            int lab = label_seq[t];
            __half2 bp = __builtin_bit_cast(__half2, wespk[tid * 17 + (lab >> 1)]);
            float bias = (lab & 1) ? __high2float(bp) : __low2float(bp);
            float g = s + bias;
            int e = tid >> 5;
            float act;
            if (e == 2)      act = tanhf(g);
            else if (e == 6) act = softplusf(g);
            else             act = sigmoidf(g);
            act_sh[tid] = act;
        }
        __syncthreads();   // bar_C

        // ---- phase D: state update + publish (16 threads, 2 units each) ----
        if (tid < 16) {
            int q0 = 2 * tid, q1 = 2 * tid + 1;
            float dt = time_seq[t + 1] - time_seq[t];
            float ig0 = act_sh[q0],        ig1 = act_sh[q1];
            float fg0 = act_sh[32  + q0],  fg1 = act_sh[32  + q1];
            float z0  = act_sh[64  + q0],  z1  = act_sh[64  + q1];
            float oo0 = act_sh[96  + q0],  oo1 = act_sh[96  + q1];
            float ib0 = act_sh[128 + q0],  ib1 = act_sh[128 + q1];
            float fb0 = act_sh[160 + q0],  fb1 = act_sh[160 + q1];
            float dl0 = act_sh[192 + q0],  dl1 = act_sh[192 + q1];
            float c0  = fmaf(fg0, cst0, ig0 * z0);
            float c1  = fmaf(fg1, cst1, ig1 * z1);
            float cb0 = fmaf(fb0, cbs0, ib0 * z0);
            float cb1 = fmaf(fb1, cbs1, ib1 * z1);
            float ct0 = cb0 + (c0 - cb0) * expf(-dl0 * dt);
            float ct1 = cb1 + (c1 - cb1) * expf(-dl1 * dt);
            float h0  = oo0 * tanhf(ct0);
            float h1  = oo1 * tanhf(ct1);
            cst0 = ct0; cst1 = ct1; cbs0 = cb0; cbs1 = cb1;
            // publish first (critical path): f16x2 into the shared XCD L2
            unsigned pk = pkhalf2(h0, h1);
            unsigned* dst = hpub + (size_t)t * 512 + slot * 16 + tid;
            asm volatile("global_store_dword %0, %1, off sc0"
                         :: "v"(dst), "v"(pk) : "memory");
            // bookkeeping (fp32, consumed by term1/term2 after kernel end)
            size_t p = (size_t)t * H + slot * UPS + q0;
            *(float2*)&all_h [p] = make_float2(h0, h1);
            *(float2*)&all_o [p] = make_float2(oo0, oo1);
            *(float2*)&all_cb[p] = make_float2(cb0, cb1);
            *(float2*)&all_cc[p] = make_float2(c0, c1);
            *(float2*)&all_dl[p] = make_float2(dl0, dl1);
        }
        // no bar after D: wave0 proceeds to A(t+1); hazards covered by bars A-C.
    }
}

__global__ void term1_kernel(const float* __restrict__ all_h, const int* __restrict__ label_seq,
                             const float* __restrict__ w, const float* __restrict__ log_s,
                             const int* __restrict__ ignore_first, float* __restrict__ acc) {
    int beg = (*ignore_first) ? 1 : 0;
    int j = blockIdx.x;
    if (j >= (NSTEP - 1 - beg)) return;
    if (label_seq[1 + beg + j] != TGT) return;
    const float* hrow = all_h + (size_t)(beg + j) * H;
    const float* w0 = w + (TGT - 1) * H;
    float part = 0.f;
    for (int i = threadIdx.x; i < H; i += blockDim.x) part += hrow[i] * w0[i];
    __shared__ float red[4];
    part = wave_sum(part);
    if ((threadIdx.x & 63) == 0) red[threadIdx.x >> 6] = part;
    __syncthreads();
    if (threadIdx.x == 0) {
        float tot = red[0] + red[1] + red[2] + red[3];
        float s0 = expf(log_s[TGT - 1]);
        float lam = s0 * softplusf(tot / s0) + 1e-9f;
        atomicAdd(acc, logf(lam));
    }
}

__global__ void term2_kernel(const float* __restrict__ all_o, const float* __restrict__ all_cb,
                             const float* __restrict__ all_cc, const float* __restrict__ all_dl,
                             const int* __restrict__ sim_idx, const float* __restrict__ sim_time,
                             const float* __restrict__ time_seq, const float* __restrict__ w,
                             const float* __restrict__ log_s, float* __restrict__ acc) {
    int i = blockIdx.x;
    int idx = sim_idx[i];
    float dtp = sim_time[i] - time_seq[idx];
    size_t base = (size_t)idx * H;
    const float* w0 = w + (TGT - 1) * H;
    float part = 0.f;
    for (int hh = threadIdx.x; hh < H; hh += blockDim.x) {
        float cb = all_cb[base + hh];
        float cc = all_cc[base + hh];
        float dl = all_dl[base + hh];
        float oo = all_o [base + hh];
        float cs = cb + (cc - cb) * expf(-dl * dtp);
        part += oo * tanhf(cs) * w0[hh];
    }
    __shared__ float red[4];
    part = wave_sum(part);
    if ((threadIdx.x & 63) == 0) red[threadIdx.x >> 6] = part;
    __syncthreads();
    if (threadIdx.x == 0) {
        float tot = red[0] + red[1] + red[2] + red[3];
        float s0 = expf(log_s[TGT - 1]);
        float lam = s0 * softplusf(tot / s0) + 1e-9f;
        atomicAdd(acc + 1, lam);
    }
}

__global__ void finish_kernel(const float* __restrict__ acc, const float* __restrict__ time_seq,
                              float* __restrict__ out) {
    float T = time_seq[NE - 1] - time_seq[0];
    out[0] = -(acc[0] - acc[1] * (T / (float)NS));
}

extern "C" void kernel_launch(void* const* d_in, const int* in_sizes, int n_in,
                              void* d_out, int out_size, void* d_ws, size_t ws_size,
                              hipStream_t stream) {
    const int*   label_seq    = (const int*)  d_in[0];
    const float* time_seq     = (const float*)d_in[1];
    const float* sim_time     = (const float*)d_in[2];
    const int*   sim_idx      = (const int*)  d_in[3];
    const int*   ignore_first = (const int*)  d_in[4];
    const float* Emb   = (const float*)d_in[5];
    const float* W     = (const float*)d_in[6];
    const float* U     = (const float*)d_in[7];
    const float* dbias = (const float*)d_in[8];
    const float* w     = (const float*)d_in[9];
    const float* log_s = (const float*)d_in[10];
    float* out = (float*)d_out;

    float* ws = (float*)d_ws;
    size_t off = 0;
    int*      ctl  = (int*)(ws + off);      off += 16;   // [0..7] roster, [8] winner
    float*    acc  = ws + off;              off += 32;   // [0]=term1, [1]=term2-sum
    float*    EmbT = ws + off;              off += (size_t)LBLP1 * H;
    float*    WEmb = ws + off;              off += 7 * H * LBLP1;
    off = (off + 3) & ~(size_t)3;
    unsigned* Upk  = (unsigned*)(ws + off); off += (size_t)7 * H * (H / 2);
    unsigned* hpub = (unsigned*)(ws + off); off += (size_t)NSTEP * 512;
    float* all_h  = ws + off;  off += (size_t)NSTEP * H;
    float* all_o  = ws + off;  off += (size_t)NSTEP * H;
    float* all_cb = ws + off;  off += (size_t)NSTEP * H;
    float* all_cc = ws + off;  off += (size_t)NSTEP * H;
    float* all_dl = ws + off;  off += (size_t)NSTEP * H;

    hipMemsetAsync(ctl, 0, 8 * sizeof(int), stream);          // roster = 0
    hipMemsetAsync(ctl + 8, 0xFF, sizeof(int), stream);       // winner = -1
    hipMemsetAsync(acc, 0, 2 * sizeof(float), stream);
    hipMemsetAsync(hpub, 0xFF, (size_t)NSTEP * 512 * 4, stream);  // sentinel

    hipLaunchKernelGGL(embT_kernel, dim3(LBLP1), dim3(256), 0, stream, Emb, EmbT);
    hipLaunchKernelGGL(wemb_kernel, dim3(7 * H), dim3(256), 0, stream,
                       W, EmbT, dbias, WEmb);
    hipLaunchKernelGGL(upk_kernel, dim3(7 * H), dim3(256), 0, stream, U, Upk);

    // LDS: 64 U rows (32768) + h_pk (512) + wespk (3808) + act (224) + part8 (1800)
    unsigned int smem_bytes = (unsigned int)((64 * 512 + 512 + SROWS * 17 + SROWS
                                              + 8 * 225) * 4);
    hipFuncSetAttribute((const void*)scan_kernel, hipFuncAttributeMaxDynamicSharedMemorySize,
                        (int)smem_bytes);
    void* args[] = { (void*)&Upk, (void*)&WEmb, (void*)&label_seq, (void*)&time_seq,
                     (void*)&ctl, (void*)&hpub, (void*)&all_h, (void*)&all_o,
                     (void*)&all_cb, (void*)&all_cc, (void*)&all_dl };
    hipLaunchCooperativeKernel((void*)scan_kernel, dim3(NWG), dim3(THREADS),
                               args, smem_bytes, stream);

    hipLaunchKernelGGL(term1_kernel, dim3(NSTEP - 1), dim3(256), 0, stream,
                       all_h, label_seq, w, log_s, ignore_first, acc);
    hipLaunchKernelGGL(term2_kernel, dim3(NS), dim3(256), 0, stream,
                       all_o, all_cb, all_cc, all_dl, sim_idx, sim_time, time_seq, w, log_s, acc);
    hipLaunchKernelGGL(finish_kernel, dim3(1), dim3(1), 0, stream, acc, time_seq, out);
}

// Round 9
// 25091.861 us; speedup vs baseline: 5.0599x; 2.8997x over previous
//
#include <hip/hip_runtime.h>
#include <hip/hip_fp16.h>
#include <math.h>

#define H      1024
#define LBLP1  33        // LABEL_SIZE + 1
#define NE     4096
#define NS     4096
#define NSTEP  (NE - 1)  // 4095 scan steps
#define TGT    1
#define NWG    64        // scan workgroups
#define UPW    16        // units per WG (= waves per WG)
#define THREADS 1024
#define NCPY   4         // replicated publish copies (16 consumer WGs each)

__device__ __forceinline__ float wave_sum(float v) {
#pragma unroll
    for (int o = 32; o > 0; o >>= 1) v += __shfl_xor(v, o, 64);
    return v;
}
__device__ __forceinline__ float softplusf(float x) {
    return x > 0.f ? x + log1pf(expf(-x)) : log1pf(expf(x));
}
__device__ __forceinline__ float sigmoidf(float x) {
    return 1.f / (1.f + expf(-x));
}

#if __has_builtin(__builtin_amdgcn_cvt_pkrtz) && __has_builtin(__builtin_amdgcn_fdot2)
using half2_t = decltype(__builtin_amdgcn_cvt_pkrtz(0.f, 0.f));
__device__ __forceinline__ float dot2(unsigned u, unsigned h, float c) {
    return __builtin_amdgcn_fdot2(__builtin_bit_cast(half2_t, u),
                                  __builtin_bit_cast(half2_t, h), c, false);
}
#else
__device__ __forceinline__ float dot2(unsigned u, unsigned h, float c) {
    float2 fa = __half22float2(__builtin_bit_cast(__half2, u));
    float2 fb = __half22float2(__builtin_bit_cast(__half2, h));
    c = fmaf(fa.x, fb.x, c);
    c = fmaf(fa.y, fb.y, c);
    return c;
}
#endif

__device__ __forceinline__ unsigned pkhalf2(float a, float b) {
    return __builtin_bit_cast(unsigned, __floats2half2_rn(a, b));
}

// EmbT[l*H + k] = Emb[k*LBLP1 + l]
__global__ void embT_kernel(const float* __restrict__ Emb, float* __restrict__ EmbT) {
    int l = blockIdx.x;
    for (int k = threadIdx.x; k < H; k += blockDim.x)
        EmbT[(size_t)l * H + k] = Emb[(size_t)k * LBLP1 + l];
}

// WEmb[row*33 + l] = dot(W[row,:], EmbT[l,:]) + d[row];  row = e*H + h
__global__ void wemb_kernel(const float* __restrict__ W, const float* __restrict__ EmbT,
                            const float* __restrict__ dbias, float* __restrict__ WEmb) {
    int row  = blockIdx.x;
    int wave = threadIdx.x >> 6;
    int lane = threadIdx.x & 63;
    __shared__ float wrow[H];
    for (int i = threadIdx.x; i < H; i += blockDim.x) wrow[i] = W[(size_t)row * H + i];
    __syncthreads();
    float db = dbias[row];
    for (int l = wave; l < LBLP1; l += 4) {
        const float* ec = EmbT + (size_t)l * H;
        float a = 0.f;
#pragma unroll
        for (int m = 0; m < 16; ++m) {
            int k = lane + (m << 6);
            a = fmaf(wrow[k], ec[k], a);
        }
        a = wave_sum(a);
        if (lane == 0) WEmb[(size_t)row * LBLP1 + l] = a + db;
    }
}

// pack U rows fp32 -> f16x2 dwords: Upk[row][p] holds elems (2p, 2p+1)
__global__ void upk_kernel(const float* __restrict__ U, unsigned* __restrict__ Upk) {
    int row = blockIdx.x;  // 0..7*H-1
    const float4* src = (const float4*)(U + (size_t)row * H);
    uint2* dst = (uint2*)(Upk + (size_t)row * (H / 2));
    for (int j = threadIdx.x; j < H / 4; j += blockDim.x) {
        float4 f = src[j];
        dst[j] = make_uint2(pkhalf2(f.x, f.y), pkhalf2(f.z, f.w));
    }
}

// Persistent dataflow scan, tagged-dword edition.
// 64 WGs x 16 waves; wave w of WG g owns unit u = g*16+w (all 7 gates).
// Publish: one dword per unit per step: (t+1)<<16 | f16(h)  -- value+tag
// atomic, depth-2 ring, NCPY copies. Consumers: wave 0 polls 16 coalesced
// tagged dwords/lane (agent scope), packs f16 pairs into LDS. ONE barrier/step.
__global__ __launch_bounds__(THREADS)
void scan_kernel(const unsigned* __restrict__ Upk, const float* __restrict__ WEmb,
                 const int* __restrict__ label_seq, const float* __restrict__ time_seq,
                 unsigned* __restrict__ hpub,
                 float* __restrict__ all_h, float* __restrict__ all_o,
                 float* __restrict__ all_cb, float* __restrict__ all_cc,
                 float* __restrict__ all_dl) {
    const int tid  = threadIdx.x;
    const int wg   = blockIdx.x;
    const int wave = tid >> 6;
    const int lane = tid & 63;
    const int u    = wg * UPW + wave;          // this wave's hidden unit

    // ---------------- LDS layout ----------------
    extern __shared__ unsigned smem_u[];
    unsigned* uld  = smem_u;                   // 64 rows * 512 dw = 32768 (128 KB)
    unsigned* h_pk = uld + 64 * 512;           // 512 dw (packed f16 pairs)
    float*    wes  = (float*)(h_pk + 512);     // 112*33 = 3696 f
    float*    wscr = wes + 112 * LBLP1;        // 16 waves * 8 groups * 8 = 1024 f

    // ---------------- one-time staging ----------------
    // LDS rows: gates 0..3 of unit u; reg rows: gates 4..6.
#pragma unroll
    for (int e = 0; e < 4; ++e)
#pragma unroll
        for (int m = 0; m < 8; ++m)
            uld[(wave * 4 + e) * 512 + lane + (m << 6)] =
                Upk[((size_t)e * H + u) * 512 + lane + (m << 6)];
    unsigned ureg[3][8];
#pragma unroll
    for (int e = 0; e < 3; ++e)
#pragma unroll
        for (int m = 0; m < 8; ++m)
            ureg[e][m] = Upk[((size_t)(4 + e) * H + u) * 512 + lane + (m << 6)];
    // bias table rows for unit u (7 gates x 33 labels)
#pragma unroll
    for (int g = 0; g < 7; ++g)
        if (lane < LBLP1)
            wes[(wave * 7 + g) * LBLP1 + lane] = WEmb[((size_t)g * H + u) * LBLP1 + lane];
    __syncthreads();

    float c_t = 0.f, cbar = 0.f;   // used by lane 0 of each wave

    for (int t = 0; t < NSTEP; ++t) {
        const int   lab = label_seq[t];
        const float dt  = time_seq[t + 1] - time_seq[t];

        // ---- wave 0: acquire h_t (tagged dwords, agent scope), pack into LDS ----
        if (wave == 0) {
            unsigned v[16];
            if (t > 0) {
                const unsigned* src = hpub + (wg >> 4) * 2048 + (t & 1) * 1024 + lane;
                for (;;) {
                    bool ok = true;
#pragma unroll
                    for (int j = 0; j < 16; ++j)
                        v[j] = __hip_atomic_load(src + (j << 6), __ATOMIC_RELAXED,
                                                 __HIP_MEMORY_SCOPE_AGENT);
#pragma unroll
                    for (int j = 0; j < 16; ++j) ok &= ((v[j] >> 16) == (unsigned)t);
                    if (__all(ok)) break;
                }
            } else {
#pragma unroll
                for (int j = 0; j < 16; ++j) v[j] = 0u;
            }
            // pair units (2p, 2p+1) via neighbor-lane exchange; even lanes write
#pragma unroll
            for (int j = 0; j < 16; ++j) {
                unsigned vx = __shfl_xor(v[j], 1, 64);
                if ((lane & 1) == 0)
                    h_pk[(j << 5) + (lane >> 1)] = (v[j] & 0xFFFFu) | (vx << 16);
            }
        }
        __syncthreads();   // the only barrier per step

        // ---- all waves: 7 gate dots for own unit (4 LDS rows + 3 reg rows) ----
        unsigned hreg[8];
#pragma unroll
        for (int m = 0; m < 8; ++m) hreg[m] = h_pk[lane + (m << 6)];

        float p[7];
#pragma unroll
        for (int e = 0; e < 4; ++e) {
            float a = 0.f;
#pragma unroll
            for (int m = 0; m < 8; ++m)
                a = dot2(uld[(wave * 4 + e) * 512 + lane + (m << 6)], hreg[m], a);
            p[e] = a;
        }
#pragma unroll
        for (int e = 0; e < 3; ++e) {
            float a = 0.f;
#pragma unroll
            for (int m = 0; m < 8; ++m)
                a = dot2(ureg[e][m], hreg[m], a);
            p[4 + e] = a;
        }
        // 3-level butterfly (8-lane groups), then LDS cross-group reduce
#pragma unroll
        for (int g = 0; g < 7; ++g) {
            p[g] += __shfl_xor(p[g], 1, 64);
            p[g] += __shfl_xor(p[g], 2, 64);
            p[g] += __shfl_xor(p[g], 4, 64);
        }
        if ((lane & 7) == 0) {
            int grp = lane >> 3;
#pragma unroll
            for (int g = 0; g < 7; ++g)
                wscr[(wave << 6) + (grp << 3) + g] = p[g];
        }
        asm volatile("s_waitcnt lgkmcnt(0)" ::: "memory");

        float act = 0.f;
        if (lane < 7) {
            float s = 0.f;
#pragma unroll
            for (int k = 0; k < 8; ++k) s += wscr[(wave << 6) + (k << 3) + lane];
            float g = s + wes[(wave * 7 + lane) * LBLP1 + lab];
            act = (lane == 2) ? tanhf(g) : (lane == 6) ? softplusf(g) : sigmoidf(g);
        }
        float ig = __shfl(act, 0), fg = __shfl(act, 1), zz = __shfl(act, 2);
        float oo = __shfl(act, 3), ib = __shfl(act, 4), fb = __shfl(act, 5);
        float dl = __shfl(act, 6);

        // ---- lane 0: state update + tagged publish + bookkeeping ----
        if (lane == 0) {
            float c   = fmaf(fg, c_t, ig * zz);
            float cbn = fmaf(fb, cbar, ib * zz);
            float ctn = cbn + (c - cbn) * expf(-dl * dt);
            float hn  = oo * tanhf(ctn);
            c_t = ctn; cbar = cbn;
            unsigned pk = ((unsigned)(t + 1) << 16) | (pkhalf2(hn, 0.f) & 0xFFFFu);
            int slotbase = ((t + 1) & 1) * 1024 + u;
#pragma unroll
            for (int cp = 0; cp < NCPY; ++cp)
                __hip_atomic_store(&hpub[cp * 2048 + slotbase], pk,
                                   __ATOMIC_RELAXED, __HIP_MEMORY_SCOPE_AGENT);
            size_t pos = (size_t)t * H + u;
            all_h [pos] = hn;
            all_o [pos] = oo;
            all_cb[pos] = cbn;
            all_cc[pos] = c;
            all_dl[pos] = dl;
        }
        // no trailing barrier: wave0's next poll cannot complete until every
        // wave (all WGs) has published step t, which happens after their hreg
        // reads of h_pk -- so the h_pk rewrite at t+1 is hazard-free.
    }
}

__global__ void term1_kernel(const float* __restrict__ all_h, const int* __restrict__ label_seq,
                             const float* __restrict__ w, const float* __restrict__ log_s,
                             const int* __restrict__ ignore_first, float* __restrict__ acc) {
    int beg = (*ignore_first) ? 1 : 0;
    int j = blockIdx.x;
    if (j >= (NSTEP - 1 - beg)) return;
    if (label_seq[1 + beg + j] != TGT) return;
    const float* hrow = all_h + (size_t)(beg + j) * H;
    const float* w0 = w + (TGT - 1) * H;
    float part = 0.f;
    for (int i = threadIdx.x; i < H; i += blockDim.x) part += hrow[i] * w0[i];
    __shared__ float red[4];
    part = wave_sum(part);
    if ((threadIdx.x & 63) == 0) red[threadIdx.x >> 6] = part;
    __syncthreads();
    if (threadIdx.x == 0) {
        float tot = red[0] + red[1] + red[2] + red[3];
        float s0 = expf(log_s[TGT - 1]);
        float lam = s0 * softplusf(tot / s0) + 1e-9f;
        atomicAdd(acc, logf(lam));
    }
}

__global__ void term2_kernel(const float* __restrict__ all_o, const float* __restrict__ all_cb,
                             const float* __restrict__ all_cc, const float* __restrict__ all_dl,
                             const int* __restrict__ sim_idx, const float* __restrict__ sim_time,
                             const float* __restrict__ time_seq, const float* __restrict__ w,
                             const float* __restrict__ log_s, float* __restrict__ acc) {
    int i = blockIdx.x;
    int idx = sim_idx[i];
    float dtp = sim_time[i] - time_seq[idx];
    size_t base = (size_t)idx * H;
    const float* w0 = w + (TGT - 1) * H;
    float part = 0.f;
    for (int hh = threadIdx.x; hh < H; hh += blockDim.x) {
        float cb = all_cb[base + hh];
        float cc = all_cc[base + hh];
        float dl = all_dl[base + hh];
        float oo = all_o [base + hh];
        float cs = cb + (cc - cb) * expf(-dl * dtp);
        part += oo * tanhf(cs) * w0[hh];
    }
    __shared__ float red[4];
    part = wave_sum(part);
    if ((threadIdx.x & 63) == 0) red[threadIdx.x >> 6] = part;
    __syncthreads();
    if (threadIdx.x == 0) {
        float tot = red[0] + red[1] + red[2] + red[3];
        float s0 = expf(log_s[TGT - 1]);
        float lam = s0 * softplusf(tot / s0) + 1e-9f;
        atomicAdd(acc + 1, lam);
    }
}

__global__ void finish_kernel(const float* __restrict__ acc, const float* __restrict__ time_seq,
                              float* __restrict__ out) {
    float T = time_seq[NE - 1] - time_seq[0];
    out[0] = -(acc[0] - acc[1] * (T / (float)NS));
}

extern "C" void kernel_launch(void* const* d_in, const int* in_sizes, int n_in,
                              void* d_out, int out_size, void* d_ws, size_t ws_size,
                              hipStream_t stream) {
    const int*   label_seq    = (const int*)  d_in[0];
    const float* time_seq     = (const float*)d_in[1];
    const float* sim_time     = (const float*)d_in[2];
    const int*   sim_idx      = (const int*)  d_in[3];
    const int*   ignore_first = (const int*)  d_in[4];
    const float* Emb   = (const float*)d_in[5];
    const float* W     = (const float*)d_in[6];
    const float* U     = (const float*)d_in[7];
    const float* dbias = (const float*)d_in[8];
    const float* w     = (const float*)d_in[9];
    const float* log_s = (const float*)d_in[10];
    float* out = (float*)d_out;

    float* ws = (float*)d_ws;
    size_t off = 0;
    float*    acc  = ws + off;              off += 32;   // [0]=term1, [1]=term2-sum
    float*    EmbT = ws + off;              off += (size_t)LBLP1 * H;
    float*    WEmb = ws + off;              off += (size_t)7 * H * LBLP1;
    off = (off + 3) & ~(size_t)3;
    unsigned* Upk  = (unsigned*)(ws + off); off += (size_t)7 * H * (H / 2);
    unsigned* hpub = (unsigned*)(ws + off); off += (size_t)NCPY * 2048;   // tagged ring
    float* all_h  = ws + off;  off += (size_t)NSTEP * H;
    float* all_o  = ws + off;  off += (size_t)NSTEP * H;
    float* all_cb = ws + off;  off += (size_t)NSTEP * H;
    float* all_cc = ws + off;  off += (size_t)NSTEP * H;
    float* all_dl = ws + off;  off += (size_t)NSTEP * H;

    hipMemsetAsync(acc, 0, 2 * sizeof(float), stream);
    hipMemsetAsync(hpub, 0, (size_t)NCPY * 2048 * sizeof(unsigned), stream);  // tag 0

    hipLaunchKernelGGL(embT_kernel, dim3(LBLP1), dim3(256), 0, stream, Emb, EmbT);
    hipLaunchKernelGGL(wemb_kernel, dim3(7 * H), dim3(256), 0, stream,
                       W, EmbT, dbias, WEmb);
    hipLaunchKernelGGL(upk_kernel, dim3(7 * H), dim3(256), 0, stream, U, Upk);

    // LDS: 64 U rows (131072 B) + h_pk (2048 B) + wes (14784 B) + wscr (4096 B)
    unsigned int smem_bytes = (unsigned int)((64 * 512 + 512) * 4
                                             + (112 * LBLP1 + 16 * 64) * 4);
    hipFuncSetAttribute((const void*)scan_kernel, hipFuncAttributeMaxDynamicSharedMemorySize,
                        (int)smem_bytes);
    void* args[] = { (void*)&Upk, (void*)&WEmb, (void*)&label_seq, (void*)&time_seq,
                     (void*)&hpub, (void*)&all_h, (void*)&all_o, (void*)&all_cb,
                     (void*)&all_cc, (void*)&all_dl };
    // cooperative launch only for the co-residency guarantee (no grid.sync inside)
    hipLaunchCooperativeKernel((void*)scan_kernel, dim3(NWG), dim3(THREADS),
                               args, smem_bytes, stream);

    hipLaunchKernelGGL(term1_kernel, dim3(NSTEP - 1), dim3(256), 0, stream,
                       all_h, label_seq, w, log_s, ignore_first, acc);
    hipLaunchKernelGGL(term2_kernel, dim3(NS), dim3(256), 0, stream,
                       all_o, all_cb, all_cc, all_dl, sim_idx, sim_time, time_seq, w, log_s, acc);
    hipLaunchKernelGGL(finish_kernel, dim3(1), dim3(1), 0, stream, acc, time_seq, out);
}

// Round 10
// 17160.834 us; speedup vs baseline: 7.3983x; 1.4622x over previous
//
#include <hip/hip_runtime.h>
#include <math.h>

#define H      1024
#define LBLP1  33        // LABEL_SIZE + 1
#define NE     4096
#define NS     4096
#define NSTEP  (NE - 1)  // 4095 scan steps
#define TGT    1
#define NWG    256       // scan workgroups, 4 units each
#define UPW    4
#define ROWS   28        // 7 gates * 4 units
#define THREADS 256      // 4 waves; wave w owns unit wg*4+w
#define NCPY   4         // replicated h copies (64 consumer WGs each)
#define SENT   0xFFFFFFFFu

__device__ __forceinline__ float wave_sum(float v) {
#pragma unroll
    for (int o = 32; o > 0; o >>= 1) v += __shfl_xor(v, o, 64);
    return v;
}
__device__ __forceinline__ float softplusf(float x) {
    return x > 0.f ? x + log1pf(expf(-x)) : log1pf(expf(x));
}
__device__ __forceinline__ float sigmoidf(float x) {
    return 1.f / (1.f + expf(-x));
}
// round-to-nearest-even fp32 -> bf16 (|h|<1 so 0xFFFF never produced)
__device__ __forceinline__ unsigned short f2bf(float f) {
    unsigned u = __float_as_uint(f);
    return (unsigned short)((u + 0x7FFFu + ((u >> 16) & 1u)) >> 16);
}

// EmbT[l*H + k] = Emb[k*LBLP1 + l]
__global__ void embT_kernel(const float* __restrict__ Emb, float* __restrict__ EmbT) {
    int l = blockIdx.x;
    for (int k = threadIdx.x; k < H; k += blockDim.x)
        EmbT[(size_t)l * H + k] = Emb[(size_t)k * LBLP1 + l];
}

// WEmb[row*33 + l] = dot(W[row,:], EmbT[l,:]) + d[row];  row = e*H + h
__global__ void wemb_kernel(const float* __restrict__ W, const float* __restrict__ EmbT,
                            const float* __restrict__ dbias, float* __restrict__ WEmb) {
    int row  = blockIdx.x;
    int wave = threadIdx.x >> 6;
    int lane = threadIdx.x & 63;
    __shared__ float wrow[H];
    for (int i = threadIdx.x; i < H; i += blockDim.x) wrow[i] = W[(size_t)row * H + i];
    __syncthreads();
    float db = dbias[row];
    for (int l = wave; l < LBLP1; l += 4) {
        const float* ec = EmbT + (size_t)l * H;
        float a = 0.f;
#pragma unroll
        for (int m = 0; m < 16; ++m) {
            int k = lane + (m << 6);
            a = fmaf(wrow[k], ec[k], a);
        }
        a = wave_sum(a);
        if (lane == 0) WEmb[(size_t)row * LBLP1 + l] = a + db;
    }
}

// Persistent dataflow scan. 256 WGs x 4 waves; wave w owns unit wg*4+w fully:
// 7 gate dots + reduce + activations + state update all wave-local.
// h exchange: one packed 8B bf16 agent store per WG into NCPY copies (R5 path);
// wave 0 polls 8 coalesced dwords/lane from its copy. Two 4-wave barriers/step.
__global__ __launch_bounds__(THREADS)
void scan_kernel(const float* __restrict__ WEmb, const float* __restrict__ U,
                 const int* __restrict__ label_seq, const float* __restrict__ time_seq,
                 unsigned short* __restrict__ hcp,
                 float* __restrict__ all_h, float* __restrict__ all_o,
                 float* __restrict__ all_cb, float* __restrict__ all_cc,
                 float* __restrict__ all_dl) {
    const int tid  = threadIdx.x;
    const int wg   = blockIdx.x;
    const int wave = tid >> 6;
    const int lane = tid & 63;
    const int mycopy = wg >> 6;                // 64 WGs per copy
    const int u    = wg * UPW + wave;          // this wave's hidden unit

    extern __shared__ float smem[];
    float*    Uld    = smem;                   // ROWS * H              (114688 B)
    unsigned* h_pk   = (unsigned*)(Uld + ROWS * H);   // 512 dw packed bf16 pairs
    float*    wes    = (float*)(h_pk + 512);   // ROWS * 33
    float*    wscr   = wes + ROWS * LBLP1;     // 4 waves * 64
    float*    h_slot = wscr + 4 * 64;          // 4

    // ---------------- one-time staging ----------------
    for (int idx = tid; idx < ROWS * H; idx += THREADS) {
        int r = idx >> 10, k = idx & (H - 1);
        int e = r >> 2, j = r & 3;
        Uld[idx] = U[((size_t)e * H + (wg * UPW + j)) * H + k];
    }
    for (int idx = tid; idx < ROWS * LBLP1; idx += THREADS) {
        int r = idx / LBLP1, l = idx - r * LBLP1;
        int e = r >> 2, j = r & 3;
        wes[idx] = WEmb[((size_t)e * H + (wg * UPW + j)) * LBLP1 + l];
    }
    __syncthreads();

    float c_t = 0.f, cbar = 0.f;   // lane 0 of each wave

    for (int t = 0; t < NSTEP; ++t) {
        const int   lab = label_seq[t];
        const float dt  = time_seq[t + 1] - time_seq[t];

        // ---- wave 0: acquire packed h_t (8 dwords/lane, agent scope) ----
        if (wave == 0) {
            unsigned v[8];
            if (t > 0) {
                const unsigned* src = (const unsigned*)hcp
                    + ((size_t)mycopy * NSTEP + (t - 1)) * 512 + lane;
                for (;;) {
                    bool ok = true;
#pragma unroll
                    for (int j = 0; j < 8; ++j)
                        v[j] = __hip_atomic_load(src + (j << 6), __ATOMIC_RELAXED,
                                                 __HIP_MEMORY_SCOPE_AGENT);
#pragma unroll
                    for (int j = 0; j < 8; ++j) ok &= (v[j] != SENT);
                    if (ok) break;
                }
            } else {
#pragma unroll
                for (int j = 0; j < 8; ++j) v[j] = 0u;
            }
#pragma unroll
            for (int j = 0; j < 8; ++j) h_pk[(j << 6) + lane] = v[j];
        }
        __syncthreads();   // bar_A: h_pk ready

        // ---- unpack h fragment once (16 elems/lane) ----
        float2 hf[8];
#pragma unroll
        for (int m = 0; m < 8; ++m) {
            unsigned hv = h_pk[(m << 6) + lane];
            hf[m].x = __uint_as_float(hv << 16);
            hf[m].y = __uint_as_float(hv & 0xFFFF0000u);
        }

        // ---- 7 gate dots for own unit (rows r = e*4 + wave) ----
        float p[7];
#pragma unroll
        for (int e = 0; e < 7; ++e) {
            const float2* u2 = (const float2*)(Uld + (((e << 2) + wave) << 10));
            float a = 0.f;
#pragma unroll
            for (int m = 0; m < 8; ++m) {
                float2 uu = u2[(m << 6) + lane];
                a = fmaf(uu.x, hf[m].x, a);
                a = fmaf(uu.y, hf[m].y, a);
            }
            p[e] = a;
        }
        // 3-level butterfly -> 8-lane-group partials -> LDS (wave-local)
#pragma unroll
        for (int e = 0; e < 7; ++e) {
            p[e] += __shfl_xor(p[e], 1, 64);
            p[e] += __shfl_xor(p[e], 2, 64);
            p[e] += __shfl_xor(p[e], 4, 64);
        }
        if ((lane & 7) == 0) {
            int grp = lane >> 3;
#pragma unroll
            for (int e = 0; e < 7; ++e)
                wscr[(wave << 6) + (grp << 3) + e] = p[e];
        }
        asm volatile("s_waitcnt lgkmcnt(0)" ::: "memory");

        // ---- lanes 0..6: final sum + bias + activation (parallel transcendentals)
        float act = 0.f;
        if (lane < 7) {
            float s = 0.f;
#pragma unroll
            for (int k = 0; k < 8; ++k) s += wscr[(wave << 6) + (k << 3) + lane];
            float g = s + wes[((lane << 2) + wave) * LBLP1 + lab];
            act = (lane == 2) ? tanhf(g) : (lane == 6) ? softplusf(g) : sigmoidf(g);
        }
        float ig = __shfl(act, 0), fg = __shfl(act, 1), zz = __shfl(act, 2);
        float oo = __shfl(act, 3), ib = __shfl(act, 4), fb = __shfl(act, 5);
        float dl = __shfl(act, 6);

        // ---- lane 0: state update; stage hn for the packed publish ----
        float c = 0.f, cbn = 0.f, hn = 0.f;
        if (lane == 0) {
            c   = fmaf(fg, c_t, ig * zz);
            cbn = fmaf(fb, cbar, ib * zz);
            float ctn = cbn + (c - cbn) * expf(-dl * dt);
            hn  = oo * tanhf(ctn);
            c_t = ctn; cbar = cbn;
            h_slot[wave] = hn;
        }
        __syncthreads();   // bar_B: h_slot ready

        // ---- wave 0 lane 0: pack 4 units -> one 8B agent store per copy ----
        if (tid == 0) {
            unsigned long long pk =
                (unsigned long long)f2bf(h_slot[0])
              | ((unsigned long long)f2bf(h_slot[1]) << 16)
              | ((unsigned long long)f2bf(h_slot[2]) << 32)
              | ((unsigned long long)f2bf(h_slot[3]) << 48);
            unsigned long long* base = (unsigned long long*)hcp;
#pragma unroll
            for (int cp = 0; cp < NCPY; ++cp)
                __hip_atomic_store(base + ((size_t)cp * NSTEP + t) * 256 + wg,
                                   pk, __ATOMIC_RELAXED, __HIP_MEMORY_SCOPE_AGENT);
        }

        // ---- bookkeeping (fire-and-forget, after publish) ----
        if (lane == 0) {
            size_t pos = (size_t)t * H + u;
            all_h [pos] = hn;
            all_o [pos] = oo;
            all_cb[pos] = cbn;
            all_cc[pos] = c;
            all_dl[pos] = dl;
        }
        // h_pk rewrite at t+1 is gated by bar_A; h_slot rewrite by bar_B.
    }
}

__global__ void term1_kernel(const float* __restrict__ all_h, const int* __restrict__ label_seq,
                             const float* __restrict__ w, const float* __restrict__ log_s,
                             const int* __restrict__ ignore_first, float* __restrict__ acc) {
    int beg = (*ignore_first) ? 1 : 0;
    int j = blockIdx.x;
    if (j >= (NSTEP - 1 - beg)) return;
    if (label_seq[1 + beg + j] != TGT) return;
    const float* hrow = all_h + (size_t)(beg + j) * H;
    const float* w0 = w + (TGT - 1) * H;
    float part = 0.f;
    for (int i = threadIdx.x; i < H; i += blockDim.x) part += hrow[i] * w0[i];
    __shared__ float red[4];
    part = wave_sum(part);
    if ((threadIdx.x & 63) == 0) red[threadIdx.x >> 6] = part;
    __syncthreads();
    if (threadIdx.x == 0) {
        float tot = red[0] + red[1] + red[2] + red[3];
        float s0 = expf(log_s[TGT - 1]);
        float lam = s0 * softplusf(tot / s0) + 1e-9f;
        atomicAdd(acc, logf(lam));
    }
}

__global__ void term2_kernel(const float* __restrict__ all_o, const float* __restrict__ all_cb,
                             const float* __restrict__ all_cc, const float* __restrict__ all_dl,
                             const int* __restrict__ sim_idx, const float* __restrict__ sim_time,
                             const float* __restrict__ time_seq, const float* __restrict__ w,
                             const float* __restrict__ log_s, float* __restrict__ acc) {
    int i = blockIdx.x;
    int idx = sim_idx[i];
    float dtp = sim_time[i] - time_seq[idx];
    size_t base = (size_t)idx * H;
    const float* w0 = w + (TGT - 1) * H;
    float part = 0.f;
    for (int hh = threadIdx.x; hh < H; hh += blockDim.x) {
        float cb = all_cb[base + hh];
        float cc = all_cc[base + hh];
        float dl = all_dl[base + hh];
        float oo = all_o [base + hh];
        float cs = cb + (cc - cb) * expf(-dl * dtp);
        part += oo * tanhf(cs) * w0[hh];
    }
    __shared__ float red[4];
    part = wave_sum(part);
    if ((threadIdx.x & 63) == 0) red[threadIdx.x >> 6] = part;
    __syncthreads();
    if (threadIdx.x == 0) {
        float tot = red[0] + red[1] + red[2] + red[3];
        float s0 = expf(log_s[TGT - 1]);
        float lam = s0 * softplusf(tot / s0) + 1e-9f;
        atomicAdd(acc + 1, lam);
    }
}

__global__ void finish_kernel(const float* __restrict__ acc, const float* __restrict__ time_seq,
                              float* __restrict__ out) {
    float T = time_seq[NE - 1] - time_seq[0];
    out[0] = -(acc[0] - acc[1] * (T / (float)NS));
}

extern "C" void kernel_launch(void* const* d_in, const int* in_sizes, int n_in,
                              void* d_out, int out_size, void* d_ws, size_t ws_size,
                              hipStream_t stream) {
    const int*   label_seq    = (const int*)  d_in[0];
    const float* time_seq     = (const float*)d_in[1];
    const float* sim_time     = (const float*)d_in[2];
    const int*   sim_idx      = (const int*)  d_in[3];
    const int*   ignore_first = (const int*)  d_in[4];
    const float* Emb   = (const float*)d_in[5];
    const float* W     = (const float*)d_in[6];
    const float* U     = (const float*)d_in[7];
    const float* dbias = (const float*)d_in[8];
    const float* w     = (const float*)d_in[9];
    const float* log_s = (const float*)d_in[10];
    float* out = (float*)d_out;

    float* ws = (float*)d_ws;
    size_t off = 0;
    float* acc    = ws + off;  off += 32;                    // [0]=term1, [1]=term2-sum
    float* EmbT   = ws + off;  off += (size_t)LBLP1 * H;
    float* WEmb   = ws + off;  off += (size_t)7 * H * LBLP1;
    off = (off + 3) & ~(size_t)3;                            // 16B align
    unsigned short* hcp = (unsigned short*)(ws + off);       // NCPY*NSTEP*1024 bf16
    off += (size_t)NCPY * NSTEP * H / 2;                     // in float units
    float* all_h  = ws + off;  off += (size_t)NSTEP * H;
    float* all_o  = ws + off;  off += (size_t)NSTEP * H;
    float* all_cb = ws + off;  off += (size_t)NSTEP * H;
    float* all_cc = ws + off;  off += (size_t)NSTEP * H;
    float* all_dl = ws + off;  off += (size_t)NSTEP * H;

    hipMemsetAsync(acc, 0, 2 * sizeof(float), stream);
    // sentinel-fill the bf16 fan-out buffers (0xFFFF bf16 = NaN, never produced)
    hipMemsetAsync(hcp, 0xFF, (size_t)NCPY * NSTEP * H * sizeof(unsigned short), stream);

    hipLaunchKernelGGL(embT_kernel, dim3(LBLP1), dim3(256), 0, stream, Emb, EmbT);
    hipLaunchKernelGGL(wemb_kernel, dim3(7 * H), dim3(256), 0, stream,
                       W, EmbT, dbias, WEmb);

    // LDS: U 114688 + h_pk 2048 + wes 3696*?  (ROWS*33*4=3696B) + wscr 1024 + h_slot 16
    unsigned int smem_bytes = (unsigned int)((ROWS * H) * 4 + 512 * 4
                                             + ROWS * LBLP1 * 4 + 4 * 64 * 4 + 16);
    hipFuncSetAttribute((const void*)scan_kernel, hipFuncAttributeMaxDynamicSharedMemorySize,
                        (int)smem_bytes);
    void* args[] = { (void*)&WEmb, (void*)&U, (void*)&label_seq, (void*)&time_seq,
                     (void*)&hcp, (void*)&all_h, (void*)&all_o, (void*)&all_cb,
                     (void*)&all_cc, (void*)&all_dl };
    // cooperative launch only for the co-residency guarantee (no grid.sync inside)
    hipLaunchCooperativeKernel((void*)scan_kernel, dim3(NWG), dim3(THREADS),
                               args, smem_bytes, stream);

    hipLaunchKernelGGL(term1_kernel, dim3(NSTEP - 1), dim3(256), 0, stream,
                       all_h, label_seq, w, log_s, ignore_first, acc);
    hipLaunchKernelGGL(term2_kernel, dim3(NS), dim3(256), 0, stream,
                       all_o, all_cb, all_cc, all_dl, sim_idx, sim_time, time_seq, w, log_s, acc);
    hipLaunchKernelGGL(finish_kernel, dim3(1), dim3(1), 0, stream, acc, time_seq, out);
}